// Round 1
// baseline (4212.982 us; speedup 1.0000x reference)
//
#include <hip/hip_runtime.h>
#include <cstdint>

// MSCN forward: 4 type encoders (feat @ W + b, ReLU) -> segment-mean by idx ->
// concat [P,512] -> BatchNorm(batch stats) -> MLP 512->128->128->1.
// P=20000, H=128. All f32. CSR-gather pooling (no f32 atomics).

constexpr int P_N = 20000;
constexpr int HD  = 128;

// ---------------- histogram ----------------
__global__ void k_count(const int* __restrict__ idx, int n, int* __restrict__ counts) {
    int i = blockIdx.x * blockDim.x + threadIdx.x;
    int stride = gridDim.x * blockDim.x;
    for (; i < n; i += stride) atomicAdd(&counts[idx[i]], 1);
}

// ---------------- exclusive scan, one block per type ----------------
__global__ void k_scan(int* __restrict__ counts_all, int* __restrict__ off_all, int* __restrict__ cur_all) {
    const int type = blockIdx.x;
    int* counts = counts_all + type * P_N;
    int* offs   = off_all   + type * P_N;
    int* curs   = cur_all   + type * P_N;
    const int T = 256;
    const int CH = (P_N + T - 1) / T;  // 79
    int t = threadIdx.x;
    __shared__ int sums[T];
    __shared__ int pref[T];
    int local = 0;
    int p0 = t * CH;
    for (int i = 0; i < CH; ++i) {
        int p = p0 + i;
        if (p < P_N) local += counts[p];
    }
    sums[t] = local;
    __syncthreads();
    if (t == 0) {
        int run = 0;
        for (int j = 0; j < T; ++j) { pref[j] = run; run += sums[j]; }
    }
    __syncthreads();
    int run = pref[t];
    for (int i = 0; i < CH; ++i) {
        int p = p0 + i;
        if (p < P_N) { offs[p] = run; curs[p] = run; run += counts[p]; }
    }
}

// ---------------- CSR fill ----------------
__global__ void k_fill(const int* __restrict__ idx, int n, int* __restrict__ cur, int* __restrict__ list) {
    int i = blockIdx.x * blockDim.x + threadIdx.x;
    int stride = gridDim.x * blockDim.x;
    for (; i < n; i += stride) {
        int pos = atomicAdd(&cur[idx[i]], 1);
        list[pos] = i;
    }
}

// ---------------- fused encoder + segment-mean pool ----------------
// One block (128 threads) per plan. W^T chunk in LDS (per-lane b128 reads);
// feat rows read as wave-uniform broadcast dwordx4 from global.
template<int D, int KCH>
__global__ __launch_bounds__(128) void k_pool(
    const float* __restrict__ feat, const float* __restrict__ W, const float* __restrict__ bias,
    const int* __restrict__ offs, const int* __restrict__ counts, const int* __restrict__ list,
    float* __restrict__ x, int toff)
{
    constexpr int STR = KCH + 4;           // word stride: keeps 16B alignment, breaks 32-way stage conflict
    __shared__ float WT[128 * STR];
    __shared__ int eoffs[32];
    const int p = blockIdx.x;
    const int t = threadIdx.x;
    const int base = offs[p];
    const int cnt  = counts[p];
    const float bh = bias[t];
    float sum = 0.f;
    const char* fbase = (const char*)feat;

    for (int j0 = 0; j0 < cnt; j0 += 32) {
        const int m = min(32, cnt - j0);
        __syncthreads();   // protect eoffs/WT from previous iteration's readers
        if (t < 32) eoffs[t] = (t < m) ? list[base + j0 + t] * (int)(D * sizeof(float)) : 0;
        __syncthreads();
        int eo[32];
        #pragma unroll
        for (int e = 0; e < 32; ++e) eo[e] = eoffs[e];

        float acc[32];
        #pragma unroll
        for (int e = 0; e < 32; ++e) acc[e] = 0.f;

        for (int c0 = 0; c0 < D; c0 += KCH) {
            __syncthreads();
            // stage W^T chunk: WT[t*STR + k] = W[(c0+k)*128 + t]  (coalesced global read)
            for (int i = t; i < 128 * KCH; i += 128) {
                int k = i >> 7;
                WT[t * STR + k] = W[(c0 + k) * HD + t];
            }
            __syncthreads();
            const float* wrow = &WT[t * STR];
            for (int kq = 0; kq < KCH; kq += 8) {
                float4 wa = *(const float4*)(wrow + kq);
                float4 wb = *(const float4*)(wrow + kq + 4);
                const int kb = (c0 + kq) * 4;
                #pragma unroll
                for (int e = 0; e < 32; ++e) {
                    const char* fp = fbase + (uint32_t)(eo[e] + kb);
                    float4 fa = *(const float4*)(fp);
                    float4 fb2 = *(const float4*)(fp + 16);
                    float a = acc[e];
                    a = fmaf(fa.x, wa.x, a); a = fmaf(fa.y, wa.y, a);
                    a = fmaf(fa.z, wa.z, a); a = fmaf(fa.w, wa.w, a);
                    a = fmaf(fb2.x, wb.x, a); a = fmaf(fb2.y, wb.y, a);
                    a = fmaf(fb2.z, wb.z, a); a = fmaf(fb2.w, wb.w, a);
                    acc[e] = a;
                }
            }
        }
        #pragma unroll
        for (int e = 0; e < 32; ++e)
            if (e < m) sum += fmaxf(acc[e] + bh, 0.f);
    }
    const float inv = 1.f / (float)max(cnt, 1);
    x[(size_t)p * 512 + toff + t] = sum * inv;
}

// ---------------- BN batch stats ----------------
__global__ __launch_bounds__(512) void k_bnstats(const float* __restrict__ x, float* __restrict__ bnsum) {
    const int t = threadIdx.x;              // column 0..511
    const int r0 = blockIdx.x * 79;
    const int r1 = min(r0 + 79, P_N);
    float s = 0.f, q = 0.f;
    for (int r = r0; r < r1; ++r) {
        float v = x[(size_t)r * 512 + t];
        s += v; q += v * v;
    }
    atomicAdd(&bnsum[t], s);
    atomicAdd(&bnsum[512 + t], q);
}

__global__ __launch_bounds__(512) void k_bnfinal(const float* __restrict__ bnsum,
                                                 const float* __restrict__ gamma, const float* __restrict__ beta,
                                                 float* __restrict__ scale, float* __restrict__ shiftv) {
    const int t = threadIdx.x;
    const float invn = 1.f / (float)P_N;
    float mu  = bnsum[t] * invn;
    float var = bnsum[512 + t] * invn - mu * mu;
    float rstd = rsqrtf(fmaxf(var, 0.f) + 1e-5f);
    float sc = gamma[t] * rstd;
    scale[t]  = sc;
    shiftv[t] = beta[t] - mu * sc;
}

// ---------------- MLP head: 8 plans per block ----------------
__global__ __launch_bounds__(128) void k_head(
    const float* __restrict__ x, const float* __restrict__ scale, const float* __restrict__ shiftv,
    const float* __restrict__ W1, const float* __restrict__ b1,
    const float* __restrict__ W2, const float* __restrict__ b2,
    const float* __restrict__ W3, const float* __restrict__ b3,
    float* __restrict__ out)
{
    __shared__ float xn[512 * 12];
    __shared__ float h1s[128 * 12];
    __shared__ float h2s[128 * 12];
    __shared__ float red[2][8];
    const int t = threadIdx.x;
    const int p0 = blockIdx.x * 8;

    for (int i = t; i < 4096; i += 128) {
        int r = i >> 9;
        int k = i & 511;
        float v = x[(size_t)(p0 + r) * 512 + k];
        xn[k * 12 + r] = v * scale[k] + shiftv[k];
    }
    __syncthreads();

    float acc[8];
    #pragma unroll
    for (int r = 0; r < 8; ++r) acc[r] = 0.f;
    for (int k = 0; k < 512; ++k) {
        float w = W1[k * HD + t];
        float4 a0 = *(const float4*)&xn[k * 12];
        float4 a1 = *(const float4*)&xn[k * 12 + 4];
        acc[0] = fmaf(a0.x, w, acc[0]); acc[1] = fmaf(a0.y, w, acc[1]);
        acc[2] = fmaf(a0.z, w, acc[2]); acc[3] = fmaf(a0.w, w, acc[3]);
        acc[4] = fmaf(a1.x, w, acc[4]); acc[5] = fmaf(a1.y, w, acc[5]);
        acc[6] = fmaf(a1.z, w, acc[6]); acc[7] = fmaf(a1.w, w, acc[7]);
    }
    {
        float bb = b1[t];
        #pragma unroll
        for (int r = 0; r < 8; ++r) h1s[t * 12 + r] = fmaxf(acc[r] + bb, 0.f);
    }
    __syncthreads();

    #pragma unroll
    for (int r = 0; r < 8; ++r) acc[r] = 0.f;
    for (int k = 0; k < 128; ++k) {
        float w = W2[k * HD + t];
        float4 a0 = *(const float4*)&h1s[k * 12];
        float4 a1 = *(const float4*)&h1s[k * 12 + 4];
        acc[0] = fmaf(a0.x, w, acc[0]); acc[1] = fmaf(a0.y, w, acc[1]);
        acc[2] = fmaf(a0.z, w, acc[2]); acc[3] = fmaf(a0.w, w, acc[3]);
        acc[4] = fmaf(a1.x, w, acc[4]); acc[5] = fmaf(a1.y, w, acc[5]);
        acc[6] = fmaf(a1.z, w, acc[6]); acc[7] = fmaf(a1.w, w, acc[7]);
    }
    {
        float bb = b2[t];
        #pragma unroll
        for (int r = 0; r < 8; ++r) h2s[t * 12 + r] = fmaxf(acc[r] + bb, 0.f);
    }
    __syncthreads();

    float w3 = W3[t];
    float pr[8];
    #pragma unroll
    for (int r = 0; r < 8; ++r) pr[r] = h2s[t * 12 + r] * w3;
    #pragma unroll
    for (int r = 0; r < 8; ++r) {
        #pragma unroll
        for (int o = 32; o > 0; o >>= 1) pr[r] += __shfl_down(pr[r], o);
    }
    if ((t & 63) == 0) {
        #pragma unroll
        for (int r = 0; r < 8; ++r) red[t >> 6][r] = pr[r];
    }
    __syncthreads();
    if (t < 8) out[p0 + t] = red[0][t] + red[1][t] + b3[0];
}

extern "C" void kernel_launch(void* const* d_in, const int* in_sizes, int n_in,
                              void* d_out, int out_size, void* d_ws, size_t ws_size,
                              hipStream_t stream)
{
    const float* feats[4] = {(const float*)d_in[0], (const float*)d_in[4], (const float*)d_in[8],  (const float*)d_in[12]};
    const int*   idxs[4]  = {(const int*)d_in[1],   (const int*)d_in[5],   (const int*)d_in[9],   (const int*)d_in[13]};
    const float* Ws[4]    = {(const float*)d_in[2], (const float*)d_in[6], (const float*)d_in[10], (const float*)d_in[14]};
    const float* bs[4]    = {(const float*)d_in[3], (const float*)d_in[7], (const float*)d_in[11], (const float*)d_in[15]};
    const float* gamma = (const float*)d_in[16];
    const float* beta  = (const float*)d_in[17];
    const float* W1 = (const float*)d_in[18]; const float* b1 = (const float*)d_in[19];
    const float* W2 = (const float*)d_in[20]; const float* b2 = (const float*)d_in[21];
    const float* W3 = (const float*)d_in[22]; const float* b3 = (const float*)d_in[23];
    int Ns[4] = {in_sizes[1], in_sizes[5], in_sizes[9], in_sizes[13]};

    // ws layout (bytes): counts 0 | offs 320000 | curs 640000 | lists 960000..3520000
    //                    x 3520000 (+40.96MB) | bnsum 44480000 | scale 44484096 | shift 44486144
    char* ws = (char*)d_ws;
    int* counts = (int*)(ws + 0);
    int* offs   = (int*)(ws + 320000);
    int* curs   = (int*)(ws + 640000);
    int* lists[4];
    lists[0] = (int*)(ws + 960000);
    lists[1] = (int*)(ws + 1360000);
    lists[2] = (int*)(ws + 2960000);
    lists[3] = (int*)(ws + 3200000);
    float* x      = (float*)(ws + 3520000);
    float* bnsum  = (float*)(ws + 44480000);
    float* scale  = (float*)(ws + 44484096);
    float* shiftv = (float*)(ws + 44486144);

    hipMemsetAsync(counts, 0, 4 * P_N * sizeof(int), stream);
    hipMemsetAsync(bnsum, 0, 1024 * sizeof(float), stream);

    for (int tp = 0; tp < 4; ++tp) {
        int gb = (Ns[tp] + 255) / 256; if (gb > 2048) gb = 2048;
        k_count<<<gb, 256, 0, stream>>>(idxs[tp], Ns[tp], counts + tp * P_N);
    }
    k_scan<<<4, 256, 0, stream>>>(counts, offs, curs);
    for (int tp = 0; tp < 4; ++tp) {
        int gb = (Ns[tp] + 255) / 256; if (gb > 2048) gb = 2048;
        k_fill<<<gb, 256, 0, stream>>>(idxs[tp], Ns[tp], curs + tp * P_N, lists[tp]);
    }

    k_pool< 96, 96><<<P_N, 128, 0, stream>>>(feats[0], Ws[0], bs[0], offs + 0 * P_N, counts + 0 * P_N, lists[0], x, 0);
    k_pool<160, 80><<<P_N, 128, 0, stream>>>(feats[1], Ws[1], bs[1], offs + 1 * P_N, counts + 1 * P_N, lists[1], x, 128);
    k_pool< 64, 64><<<P_N, 128, 0, stream>>>(feats[2], Ws[2], bs[2], offs + 2 * P_N, counts + 2 * P_N, lists[2], x, 256);
    k_pool< 64, 64><<<P_N, 128, 0, stream>>>(feats[3], Ws[3], bs[3], offs + 3 * P_N, counts + 3 * P_N, lists[3], x, 384);

    k_bnstats<<<256, 512, 0, stream>>>(x, bnsum);
    k_bnfinal<<<1, 512, 0, stream>>>(bnsum, gamma, beta, scale, shiftv);
    k_head<<<P_N / 8, 128, 0, stream>>>(x, scale, shiftv, W1, b1, W2, b2, W3, b3, (float*)d_out);
}

// Round 2
// 513.742 us; speedup vs baseline: 8.2006x; 8.2006x over previous
//
#include <hip/hip_runtime.h>
#include <cstdint>

// MSCN forward, round 2: edge-parallel bf16-MFMA encoder GEMM over CSR-sorted
// edges, fused segment-sum (atomics at boundaries) -> raw sums x[P,512];
// mean-division via invc folded into BN-stats and head. Head MLP in f32.

constexpr int P_N = 20000;
constexpr int HD  = 128;

typedef __attribute__((ext_vector_type(8))) short  short8v;   // 8 bf16
typedef __attribute__((ext_vector_type(4))) float  float4v;

__device__ inline ushort f2bf(float f) {                       // RNE f32->bf16
    uint32_t u = __builtin_bit_cast(uint32_t, f);
    u += 0x7fffu + ((u >> 16) & 1u);
    return (ushort)(u >> 16);
}

// ---------------- histogram ----------------
__global__ void k_count(const int* __restrict__ idx, int n, int* __restrict__ counts) {
    int i = blockIdx.x * blockDim.x + threadIdx.x;
    int stride = gridDim.x * blockDim.x;
    for (; i < n; i += stride) atomicAdd(&counts[idx[i]], 1);
}

// ---------------- exclusive scan, one block per type ----------------
__global__ void k_scan(int* __restrict__ counts_all, int* __restrict__ off_all, int* __restrict__ cur_all) {
    const int type = blockIdx.x;
    int* counts = counts_all + type * P_N;
    int* offs   = off_all   + type * P_N;
    int* curs   = cur_all   + type * P_N;
    const int T = 256;
    const int CH = (P_N + T - 1) / T;
    int t = threadIdx.x;
    __shared__ int sums[T];
    __shared__ int pref[T];
    int local = 0;
    int p0 = t * CH;
    for (int i = 0; i < CH; ++i) {
        int p = p0 + i;
        if (p < P_N) local += counts[p];
    }
    sums[t] = local;
    __syncthreads();
    if (t == 0) {
        int run = 0;
        for (int j = 0; j < T; ++j) { pref[j] = run; run += sums[j]; }
    }
    __syncthreads();
    int run = pref[t];
    for (int i = 0; i < CH; ++i) {
        int p = p0 + i;
        if (p < P_N) { offs[p] = run; curs[p] = run; run += counts[p]; }
    }
}

// ---------------- CSR fill: sorted edge list + sorted plan ids ----------------
__global__ void k_fill(const int* __restrict__ idx, int n, int* __restrict__ cur,
                       int* __restrict__ list, int* __restrict__ splan) {
    int i = blockIdx.x * blockDim.x + threadIdx.x;
    int stride = gridDim.x * blockDim.x;
    for (; i < n; i += stride) {
        int p = idx[i];
        int pos = atomicAdd(&cur[p], 1);
        list[pos] = i;
        splan[pos] = p;
    }
}

// ---------------- W prep: transpose + bf16: WT[n][k] = bf16(W[k][n]) ----------------
__global__ void k_prepw(const float* __restrict__ W, ushort* __restrict__ WT, int D) {
    int i = blockIdx.x * blockDim.x + threadIdx.x;
    if (i >= HD * D) return;
    int n = i / D, k = i - n * D;
    WT[i] = f2bf(W[k * HD + n]);
}

// ---------------- encoder GEMM (gathered rows) + fused segment-sum ----------------
// block = 256 thr = 4 waves (2x2). BM=64 sorted edges, BN=128. No LDS for A/B:
// A = per-lane dwordx4 gathers of feat rows (f32->bf16 in reg), B = WT bf16
// fragment loads (L1-hot). LDS holds C tile for segment reduction.
template<int D>
__global__ __launch_bounds__(256) void k_enc(
    const float* __restrict__ feat, const ushort* __restrict__ WT, const float* __restrict__ bias,
    const int* __restrict__ list, const int* __restrict__ splan, int N,
    float* __restrict__ x, int toff)
{
    __shared__ float Cs[64][132];     // +4 pad: 2-way (free) on dump & scan
    __shared__ int plans[64];
    const int t = threadIdx.x;
    const int m0 = blockIdx.x * 64;
    if (t < 64) plans[t] = (m0 + t < N) ? splan[m0 + t] : -1;

    const int w = t >> 6, lane = t & 63;
    const int wr = w >> 1, wc = w & 1;
    const int lq = lane >> 4, lr = lane & 15;

    const float* ap[2];
    #pragma unroll
    for (int mf = 0; mf < 2; ++mf) {
        int m = m0 + wr * 32 + mf * 16 + lr;
        int row = list[min(m, N - 1)];
        ap[mf] = feat + (size_t)row * D;
    }
    const ushort* bp[4];
    float bval[4];
    #pragma unroll
    for (int nf = 0; nf < 4; ++nf) {
        int n = wc * 64 + nf * 16 + lr;
        bp[nf] = WT + n * D;
        bval[nf] = bias[n];
    }

    float4v acc[2][4];
    #pragma unroll
    for (int mf = 0; mf < 2; ++mf)
        #pragma unroll
        for (int nf = 0; nf < 4; ++nf) acc[mf][nf] = (float4v){0.f, 0.f, 0.f, 0.f};

    #pragma unroll
    for (int ks = 0; ks < D / 32; ++ks) {
        const int k0 = ks * 32 + lq * 8;      // lane's 8-contiguous K chunk
        short8v a[2];
        #pragma unroll
        for (int mf = 0; mf < 2; ++mf) {
            float4 x0 = *(const float4*)(ap[mf] + k0);
            float4 x1 = *(const float4*)(ap[mf] + k0 + 4);
            short8v v;
            v[0] = (short)f2bf(x0.x); v[1] = (short)f2bf(x0.y);
            v[2] = (short)f2bf(x0.z); v[3] = (short)f2bf(x0.w);
            v[4] = (short)f2bf(x1.x); v[5] = (short)f2bf(x1.y);
            v[6] = (short)f2bf(x1.z); v[7] = (short)f2bf(x1.w);
            a[mf] = v;
        }
        #pragma unroll
        for (int nf = 0; nf < 4; ++nf) {
            short8v b = *(const short8v*)(bp[nf] + k0);
            acc[0][nf] = __builtin_amdgcn_mfma_f32_16x16x32_bf16(a[0], b, acc[0][nf], 0, 0, 0);
            acc[1][nf] = __builtin_amdgcn_mfma_f32_16x16x32_bf16(a[1], b, acc[1][nf], 0, 0, 0);
        }
    }

    // dump C with bias+ReLU. C layout: col=lane&15, row=(lane>>4)*4+reg
    #pragma unroll
    for (int mf = 0; mf < 2; ++mf)
        #pragma unroll
        for (int nf = 0; nf < 4; ++nf) {
            const int col = wc * 64 + nf * 16 + lr;
            const int rb  = wr * 32 + mf * 16 + lq * 4;
            #pragma unroll
            for (int j = 0; j < 4; ++j)
                Cs[rb + j][col] = fmaxf(acc[mf][nf][j] + bval[nf], 0.f);
        }
    __syncthreads();

    // segment-sum over sorted rows; atomicAdd per (run, col)
    const int col = t & 127;
    const int r0 = (t >> 7) * 32;
    int curp = plans[r0];
    float s = 0.f;
    for (int r = r0; r < r0 + 32; ++r) {
        int p = plans[r];                       // wave-uniform
        if (p != curp) {
            if (curp >= 0) atomicAdd(&x[(size_t)curp * 512 + toff + col], s);
            s = 0.f; curp = p;
        }
        s += Cs[r][col];
    }
    if (curp >= 0) atomicAdd(&x[(size_t)curp * 512 + toff + col], s);
}

// ---------------- 1/count ----------------
__global__ void k_invc(const int* __restrict__ counts_all, float* __restrict__ invc) {
    int i = blockIdx.x * blockDim.x + threadIdx.x;
    if (i < 4 * P_N) invc[i] = 1.f / (float)max(counts_all[i], 1);
}

// ---------------- BN batch stats (on mean-pooled values) ----------------
__global__ __launch_bounds__(512) void k_bnstats(const float* __restrict__ x,
                                                 const float* __restrict__ invc,
                                                 float* __restrict__ bnsum) {
    const int t = threadIdx.x;
    const int r0 = blockIdx.x * 79;
    const int r1 = min(r0 + 79, P_N);
    const float* ic = invc + (t >> 7) * P_N;
    float s = 0.f, q = 0.f;
    for (int r = r0; r < r1; ++r) {
        float v = x[(size_t)r * 512 + t] * ic[r];
        s += v; q += v * v;
    }
    atomicAdd(&bnsum[t], s);
    atomicAdd(&bnsum[512 + t], q);
}

__global__ __launch_bounds__(512) void k_bnfinal(const float* __restrict__ bnsum,
                                                 const float* __restrict__ gamma, const float* __restrict__ beta,
                                                 float* __restrict__ scale, float* __restrict__ shiftv) {
    const int t = threadIdx.x;
    const float invn = 1.f / (float)P_N;
    float mu  = bnsum[t] * invn;
    float var = bnsum[512 + t] * invn - mu * mu;
    float rstd = rsqrtf(fmaxf(var, 0.f) + 1e-5f);
    float sc = gamma[t] * rstd;
    scale[t]  = sc;
    shiftv[t] = beta[t] - mu * sc;
}

// ---------------- MLP head: 8 plans per block ----------------
__global__ __launch_bounds__(128) void k_head(
    const float* __restrict__ x, const float* __restrict__ invc,
    const float* __restrict__ scale, const float* __restrict__ shiftv,
    const float* __restrict__ W1, const float* __restrict__ b1,
    const float* __restrict__ W2, const float* __restrict__ b2,
    const float* __restrict__ W3, const float* __restrict__ b3,
    float* __restrict__ out)
{
    __shared__ float xn[512 * 12];
    __shared__ float h1s[128 * 12];
    __shared__ float h2s[128 * 12];
    __shared__ float red[2][8];
    const int t = threadIdx.x;
    const int p0 = blockIdx.x * 8;

    for (int i = t; i < 4096; i += 128) {
        int r = i >> 9;
        int k = i & 511;
        float v = x[(size_t)(p0 + r) * 512 + k] * invc[(k >> 7) * P_N + p0 + r];
        xn[k * 12 + r] = v * scale[k] + shiftv[k];
    }
    __syncthreads();

    float acc[8];
    #pragma unroll
    for (int r = 0; r < 8; ++r) acc[r] = 0.f;
    for (int k = 0; k < 512; ++k) {
        float w = W1[k * HD + t];
        float4 a0 = *(const float4*)&xn[k * 12];
        float4 a1 = *(const float4*)&xn[k * 12 + 4];
        acc[0] = fmaf(a0.x, w, acc[0]); acc[1] = fmaf(a0.y, w, acc[1]);
        acc[2] = fmaf(a0.z, w, acc[2]); acc[3] = fmaf(a0.w, w, acc[3]);
        acc[4] = fmaf(a1.x, w, acc[4]); acc[5] = fmaf(a1.y, w, acc[5]);
        acc[6] = fmaf(a1.z, w, acc[6]); acc[7] = fmaf(a1.w, w, acc[7]);
    }
    {
        float bb = b1[t];
        #pragma unroll
        for (int r = 0; r < 8; ++r) h1s[t * 12 + r] = fmaxf(acc[r] + bb, 0.f);
    }
    __syncthreads();

    #pragma unroll
    for (int r = 0; r < 8; ++r) acc[r] = 0.f;
    for (int k = 0; k < 128; ++k) {
        float w = W2[k * HD + t];
        float4 a0 = *(const float4*)&h1s[k * 12];
        float4 a1 = *(const float4*)&h1s[k * 12 + 4];
        acc[0] = fmaf(a0.x, w, acc[0]); acc[1] = fmaf(a0.y, w, acc[1]);
        acc[2] = fmaf(a0.z, w, acc[2]); acc[3] = fmaf(a0.w, w, acc[3]);
        acc[4] = fmaf(a1.x, w, acc[4]); acc[5] = fmaf(a1.y, w, acc[5]);
        acc[6] = fmaf(a1.z, w, acc[6]); acc[7] = fmaf(a1.w, w, acc[7]);
    }
    {
        float bb = b2[t];
        #pragma unroll
        for (int r = 0; r < 8; ++r) h2s[t * 12 + r] = fmaxf(acc[r] + bb, 0.f);
    }
    __syncthreads();

    float w3 = W3[t];
    float pr[8];
    #pragma unroll
    for (int r = 0; r < 8; ++r) pr[r] = h2s[t * 12 + r] * w3;
    #pragma unroll
    for (int r = 0; r < 8; ++r) {
        #pragma unroll
        for (int o = 32; o > 0; o >>= 1) pr[r] += __shfl_down(pr[r], o);
    }
    if ((t & 63) == 0) {
        #pragma unroll
        for (int r = 0; r < 8; ++r) red[t >> 6][r] = pr[r];
    }
    __syncthreads();
    if (t < 8) out[p0 + t] = red[0][t] + red[1][t] + b3[0];
}

extern "C" void kernel_launch(void* const* d_in, const int* in_sizes, int n_in,
                              void* d_out, int out_size, void* d_ws, size_t ws_size,
                              hipStream_t stream)
{
    const float* feats[4] = {(const float*)d_in[0], (const float*)d_in[4], (const float*)d_in[8],  (const float*)d_in[12]};
    const int*   idxs[4]  = {(const int*)d_in[1],   (const int*)d_in[5],   (const int*)d_in[9],   (const int*)d_in[13]};
    const float* Ws[4]    = {(const float*)d_in[2], (const float*)d_in[6], (const float*)d_in[10], (const float*)d_in[14]};
    const float* bs[4]    = {(const float*)d_in[3], (const float*)d_in[7], (const float*)d_in[11], (const float*)d_in[15]};
    const float* gamma = (const float*)d_in[16];
    const float* beta  = (const float*)d_in[17];
    const float* W1 = (const float*)d_in[18]; const float* b1 = (const float*)d_in[19];
    const float* W2 = (const float*)d_in[20]; const float* b2 = (const float*)d_in[21];
    const float* W3 = (const float*)d_in[22]; const float* b3 = (const float*)d_in[23];
    int Ns[4] = {in_sizes[1], in_sizes[5], in_sizes[9], in_sizes[13]};
    const int Ds[4] = {96, 160, 64, 64};

    // ws layout (bytes)
    char* ws = (char*)d_ws;
    int* counts = (int*)(ws + 0);            // 4*P ints
    int* offs   = (int*)(ws + 320000);
    int* curs   = (int*)(ws + 640000);
    int* lists[4];
    lists[0] = (int*)(ws + 960000);          // 100000
    lists[1] = (int*)(ws + 1360000);         // 400000
    lists[2] = (int*)(ws + 2960000);         // 60000
    lists[3] = (int*)(ws + 3200000);         // 80000 -> ends 3520000
    int* splans[4];
    splans[0] = (int*)(ws + 3520000);
    splans[1] = (int*)(ws + 3920000);
    splans[2] = (int*)(ws + 5520000);
    splans[3] = (int*)(ws + 5760000);        // ends 6080000
    ushort* WTs[4];
    WTs[0] = (ushort*)(ws + 6080000);        // 128*96*2  = 24576
    WTs[1] = (ushort*)(ws + 6104576);        // 128*160*2 = 40960
    WTs[2] = (ushort*)(ws + 6145536);        // 128*64*2  = 16384
    WTs[3] = (ushort*)(ws + 6161920);        // -> 6178304
    float* invc   = (float*)(ws + 6178304);  // 4*P floats -> 6498304
    float* x      = (float*)(ws + 6498304);  // P*512 f32 = 40.96MB -> 47458304
    float* bnsum  = (float*)(ws + 47458304); // 1024 f32
    float* scale  = (float*)(ws + 47462400);
    float* shiftv = (float*)(ws + 47464448);

    hipMemsetAsync(counts, 0, 4 * P_N * sizeof(int), stream);
    hipMemsetAsync(bnsum, 0, 1024 * sizeof(float), stream);
    hipMemsetAsync(x, 0, (size_t)P_N * 512 * sizeof(float), stream);

    for (int tp = 0; tp < 4; ++tp) {
        int gb = (Ns[tp] + 255) / 256; if (gb > 2048) gb = 2048;
        k_count<<<gb, 256, 0, stream>>>(idxs[tp], Ns[tp], counts + tp * P_N);
    }
    k_scan<<<4, 256, 0, stream>>>(counts, offs, curs);
    for (int tp = 0; tp < 4; ++tp) {
        int gb = (Ns[tp] + 255) / 256; if (gb > 2048) gb = 2048;
        k_fill<<<gb, 256, 0, stream>>>(idxs[tp], Ns[tp], curs + tp * P_N, lists[tp], splans[tp]);
        k_prepw<<<(HD * Ds[tp] + 255) / 256, 256, 0, stream>>>(Ws[tp], WTs[tp], Ds[tp]);
    }

    k_enc< 96><<<(Ns[0] + 63) / 64, 256, 0, stream>>>(feats[0], WTs[0], bs[0], lists[0], splans[0], Ns[0], x, 0);
    k_enc<160><<<(Ns[1] + 63) / 64, 256, 0, stream>>>(feats[1], WTs[1], bs[1], lists[1], splans[1], Ns[1], x, 128);
    k_enc< 64><<<(Ns[2] + 63) / 64, 256, 0, stream>>>(feats[2], WTs[2], bs[2], lists[2], splans[2], Ns[2], x, 256);
    k_enc< 64><<<(Ns[3] + 63) / 64, 256, 0, stream>>>(feats[3], WTs[3], bs[3], lists[3], splans[3], Ns[3], x, 384);

    k_invc<<<(4 * P_N + 255) / 256, 256, 0, stream>>>(counts, invc);
    k_bnstats<<<256, 512, 0, stream>>>(x, invc, bnsum);
    k_bnfinal<<<1, 512, 0, stream>>>(bnsum, gamma, beta, scale, shiftv);
    k_head<<<P_N / 8, 128, 0, stream>>>(x, invc, scale, shiftv, W1, b1, W2, b2, W3, b3, (float*)d_out);
}

// Round 3
// 471.647 us; speedup vs baseline: 8.9325x; 1.0893x over previous
//
#include <hip/hip_runtime.h>
#include <cstdint>

// MSCN forward, round 3:
//  - k_enc v3: per-wave 16x128 tile (rows gathered ONCE per block), full
//    register staging of A (one vmcnt wait), 17.4KB LDS C-tile (2 passes).
//  - k_head v2: bf16-MFMA fused BN+MLP head (64 plans/block).

constexpr int P_N = 20000;
constexpr int HD  = 128;

typedef __attribute__((ext_vector_type(8))) short  short8v;
typedef __attribute__((ext_vector_type(4))) float  float4v;

__device__ inline ushort f2bf(float f) {                       // RNE f32->bf16
    uint32_t u = __builtin_bit_cast(uint32_t, f);
    u += 0x7fffu + ((u >> 16) & 1u);
    return (ushort)(u >> 16);
}
__device__ inline short8v cvt8(float4 x0, float4 x1) {
    short8v v;
    v[0] = (short)f2bf(x0.x); v[1] = (short)f2bf(x0.y);
    v[2] = (short)f2bf(x0.z); v[3] = (short)f2bf(x0.w);
    v[4] = (short)f2bf(x1.x); v[5] = (short)f2bf(x1.y);
    v[6] = (short)f2bf(x1.z); v[7] = (short)f2bf(x1.w);
    return v;
}

// ---------------- histogram ----------------
__global__ void k_count(const int* __restrict__ idx, int n, int* __restrict__ counts) {
    int i = blockIdx.x * blockDim.x + threadIdx.x;
    int stride = gridDim.x * blockDim.x;
    for (; i < n; i += stride) atomicAdd(&counts[idx[i]], 1);
}

// ---------------- exclusive scan, one block per type ----------------
__global__ void k_scan(int* __restrict__ counts_all, int* __restrict__ off_all, int* __restrict__ cur_all) {
    const int type = blockIdx.x;
    int* counts = counts_all + type * P_N;
    int* offs   = off_all   + type * P_N;
    int* curs   = cur_all   + type * P_N;
    const int T = 256;
    const int CH = (P_N + T - 1) / T;
    int t = threadIdx.x;
    __shared__ int sums[T];
    __shared__ int pref[T];
    int local = 0;
    int p0 = t * CH;
    for (int i = 0; i < CH; ++i) {
        int p = p0 + i;
        if (p < P_N) local += counts[p];
    }
    sums[t] = local;
    __syncthreads();
    if (t == 0) {
        int run = 0;
        for (int j = 0; j < T; ++j) { pref[j] = run; run += sums[j]; }
    }
    __syncthreads();
    int run = pref[t];
    for (int i = 0; i < CH; ++i) {
        int p = p0 + i;
        if (p < P_N) { offs[p] = run; curs[p] = run; run += counts[p]; }
    }
}

// ---------------- CSR fill ----------------
__global__ void k_fill(const int* __restrict__ idx, int n, int* __restrict__ cur,
                       int* __restrict__ list, int* __restrict__ splan) {
    int i = blockIdx.x * blockDim.x + threadIdx.x;
    int stride = gridDim.x * blockDim.x;
    for (; i < n; i += stride) {
        int p = idx[i];
        int pos = atomicAdd(&cur[p], 1);
        list[pos] = i;
        splan[pos] = p;
    }
}

// ---------------- W prep: WT[n][k] = bf16(W[k][n]) ----------------
__global__ void k_prepw(const float* __restrict__ W, ushort* __restrict__ WT, int D) {
    int i = blockIdx.x * blockDim.x + threadIdx.x;
    if (i >= HD * D) return;
    int n = i / D, k = i - n * D;
    WT[i] = f2bf(W[k * HD + n]);
}

// ---------------- encoder GEMM + fused segment-sum, v3 ----------------
// 4 waves, each 16 rows x 128 cols: each row gathered once per block.
template<int D>
__global__ __launch_bounds__(256) void k_enc(
    const float* __restrict__ feat, const ushort* __restrict__ WT, const float* __restrict__ bias,
    const int* __restrict__ list, const int* __restrict__ splan, int N,
    float* __restrict__ x, int toff)
{
    constexpr int NKS = D / 32;
    __shared__ float Cs[64][68];
    __shared__ int plans[64];
    const int t = threadIdx.x;
    const int m0 = blockIdx.x * 64;
    if (t < 64) plans[t] = (m0 + t < N) ? splan[m0 + t] : -1;
    const int w = t >> 6, lane = t & 63;
    const int lq = lane >> 4, lr = lane & 15;

    const int m = m0 + w * 16 + lr;
    const float* ap = feat + (size_t)list[min(m, N - 1)] * D;

    float bval[8];
    #pragma unroll
    for (int nf = 0; nf < 8; ++nf) bval[nf] = bias[nf * 16 + lr];

    // stage ALL gather chunks (one wait), then convert
    float4 st[2 * NKS];
    #pragma unroll
    for (int ks = 0; ks < NKS; ++ks) {
        st[2 * ks]     = *(const float4*)(ap + ks * 32 + lq * 8);
        st[2 * ks + 1] = *(const float4*)(ap + ks * 32 + lq * 8 + 4);
    }
    short8v a[NKS];
    #pragma unroll
    for (int ks = 0; ks < NKS; ++ks) a[ks] = cvt8(st[2 * ks], st[2 * ks + 1]);

    float4v acc[8];
    #pragma unroll
    for (int nf = 0; nf < 8; ++nf) acc[nf] = (float4v){0.f, 0.f, 0.f, 0.f};

    const ushort* wp = WT + lr * D + lq * 8;        // + nf*16*D + ks*32
    #pragma unroll
    for (int ks = 0; ks < NKS; ++ks) {
        #pragma unroll
        for (int nf = 0; nf < 8; ++nf) {
            short8v b = *(const short8v*)(wp + nf * 16 * D + ks * 32);
            acc[nf] = __builtin_amdgcn_mfma_f32_16x16x32_bf16(a[ks], b, acc[nf], 0, 0, 0);
        }
    }

    // two half-width dump+reduce passes (halves LDS)
    #pragma unroll
    for (int p = 0; p < 2; ++p) {
        __syncthreads();
        #pragma unroll
        for (int nfh = 0; nfh < 4; ++nfh) {
            const int nf = p * 4 + nfh;
            const int colh = nfh * 16 + lr;
            const int rb = w * 16 + lq * 4;
            #pragma unroll
            for (int j = 0; j < 4; ++j)
                Cs[rb + j][colh] = fmaxf(acc[nf][j] + bval[nf], 0.f);
        }
        __syncthreads();
        // segment-sum: thread = (col 0..63, rowgroup 0..3 = wave)
        const int colg = (t & 63) + p * 64 + toff;
        const int r0 = (t >> 6) * 16;
        int curp = plans[r0];
        float s = 0.f;
        for (int r = r0; r < r0 + 16; ++r) {
            int pl = plans[r];                      // wave-uniform
            if (pl != curp) {
                if (curp >= 0) atomicAdd(&x[(size_t)curp * 512 + colg], s);
                s = 0.f; curp = pl;
            }
            s += Cs[r][t & 63];
        }
        if (curp >= 0) atomicAdd(&x[(size_t)curp * 512 + colg], s);
    }
}

// ---------------- 1/count ----------------
__global__ void k_invc(const int* __restrict__ counts_all, float* __restrict__ invc) {
    int i = blockIdx.x * blockDim.x + threadIdx.x;
    if (i < 4 * P_N) invc[i] = 1.f / (float)max(counts_all[i], 1);
}

// ---------------- BN batch stats ----------------
__global__ __launch_bounds__(512) void k_bnstats(const float* __restrict__ x,
                                                 const float* __restrict__ invc,
                                                 float* __restrict__ bnsum) {
    const int t = threadIdx.x;
    const int r0 = blockIdx.x * 79;
    const int r1 = min(r0 + 79, P_N);
    const float* ic = invc + (t >> 7) * P_N;
    float s = 0.f, q = 0.f;
    for (int r = r0; r < r1; ++r) {
        float v = x[(size_t)r * 512 + t] * ic[r];
        s += v; q += v * v;
    }
    atomicAdd(&bnsum[t], s);
    atomicAdd(&bnsum[512 + t], q);
}

__global__ __launch_bounds__(512) void k_bnfinal(const float* __restrict__ bnsum,
                                                 const float* __restrict__ gamma, const float* __restrict__ beta,
                                                 float* __restrict__ scale, float* __restrict__ shiftv) {
    const int t = threadIdx.x;
    const float invn = 1.f / (float)P_N;
    float mu  = bnsum[t] * invn;
    float var = bnsum[512 + t] * invn - mu * mu;
    float rstd = rsqrtf(fmaxf(var, 0.f) + 1e-5f);
    float sc = gamma[t] * rstd;
    scale[t]  = sc;
    shiftv[t] = beta[t] - mu * sc;
}

// ---------------- fused MFMA head: BN + 512->128->128->1, 64 plans/block ----
__global__ __launch_bounds__(256) void k_head(
    const float* __restrict__ x, const float* __restrict__ invc,
    const float* __restrict__ scale, const float* __restrict__ shiftv,
    const ushort* __restrict__ WT1, const float* __restrict__ b1,
    const ushort* __restrict__ WT2, const float* __restrict__ b2,
    const float* __restrict__ W3, const float* __restrict__ b3,
    float* __restrict__ out)
{
    __shared__ float h[4][16][132];     // per-wave h1 transpose buffer
    const int t = threadIdx.x;
    const int w = t >> 6, lane = t & 63;
    const int lq = lane >> 4, lr = lane & 15;
    const int p0 = blockIdx.x * 64;
    const int row = p0 + w * 16 + lr;
    const int rowc = min(row, P_N - 1);
    const float* xr = x + (size_t)rowc * 512;

    // ---- layer 1: [64,512] @ [512,128] ----
    float4v acc[8];
    #pragma unroll
    for (int nf = 0; nf < 8; ++nf) acc[nf] = (float4v){0.f, 0.f, 0.f, 0.f};

    #pragma unroll
    for (int kc = 0; kc < 4; ++kc) {          // 128-wide chunk = one type
        const float ic = invc[kc * P_N + rowc];
        float4 st[8];
        #pragma unroll
        for (int k2 = 0; k2 < 4; ++k2) {
            const int k0 = kc * 128 + k2 * 32 + lq * 8;
            st[2 * k2]     = *(const float4*)(xr + k0);
            st[2 * k2 + 1] = *(const float4*)(xr + k0 + 4);
        }
        short8v a[4];
        #pragma unroll
        for (int k2 = 0; k2 < 4; ++k2) {
            const int k0 = kc * 128 + k2 * 32 + lq * 8;
            float4 sc0 = *(const float4*)(scale + k0);
            float4 sc1 = *(const float4*)(scale + k0 + 4);
            float4 sh0 = *(const float4*)(shiftv + k0);
            float4 sh1 = *(const float4*)(shiftv + k0 + 4);
            float4 v0, v1;
            v0.x = st[2*k2].x   * ic * sc0.x + sh0.x;
            v0.y = st[2*k2].y   * ic * sc0.y + sh0.y;
            v0.z = st[2*k2].z   * ic * sc0.z + sh0.z;
            v0.w = st[2*k2].w   * ic * sc0.w + sh0.w;
            v1.x = st[2*k2+1].x * ic * sc1.x + sh1.x;
            v1.y = st[2*k2+1].y * ic * sc1.y + sh1.y;
            v1.z = st[2*k2+1].z * ic * sc1.z + sh1.z;
            v1.w = st[2*k2+1].w * ic * sc1.w + sh1.w;
            a[k2] = cvt8(v0, v1);
        }
        #pragma unroll
        for (int k2 = 0; k2 < 4; ++k2) {
            const int ks = kc * 4 + k2;
            #pragma unroll
            for (int nf = 0; nf < 8; ++nf) {
                short8v b = *(const short8v*)(WT1 + (nf * 16 + lr) * 512 + ks * 32 + lq * 8);
                acc[nf] = __builtin_amdgcn_mfma_f32_16x16x32_bf16(a[k2], b, acc[nf], 0, 0, 0);
            }
        }
    }
    // h1 = ReLU(acc + b1) -> LDS transpose
    #pragma unroll
    for (int nf = 0; nf < 8; ++nf) {
        const float bv = b1[nf * 16 + lr];
        #pragma unroll
        for (int j = 0; j < 4; ++j)
            h[w][lq * 4 + j][nf * 16 + lr] = fmaxf(acc[nf][j] + bv, 0.f);
    }
    __syncthreads();

    // ---- layer 2: [64,128] @ [128,128] ----
    float4v acc2[8];
    #pragma unroll
    for (int nf = 0; nf < 8; ++nf) acc2[nf] = (float4v){0.f, 0.f, 0.f, 0.f};
    short8v a2[4];
    #pragma unroll
    for (int ks = 0; ks < 4; ++ks) {
        const float* hp = &h[w][lr][ks * 32 + lq * 8];
        float4 h0 = *(const float4*)hp;
        float4 h1v = *(const float4*)(hp + 4);
        a2[ks] = cvt8(h0, h1v);
    }
    #pragma unroll
    for (int ks = 0; ks < 4; ++ks) {
        #pragma unroll
        for (int nf = 0; nf < 8; ++nf) {
            short8v b = *(const short8v*)(WT2 + (nf * 16 + lr) * 128 + ks * 32 + lq * 8);
            acc2[nf] = __builtin_amdgcn_mfma_f32_16x16x32_bf16(a2[ks], b, acc2[nf], 0, 0, 0);
        }
    }

    // ---- layer 3: dot(ReLU(h2 + b2), W3) in-register ----
    float s0 = 0.f, s1 = 0.f, s2 = 0.f, s3 = 0.f;
    #pragma unroll
    for (int nf = 0; nf < 8; ++nf) {
        const int col = nf * 16 + lr;
        const float w3v = W3[col];
        const float bv = b2[col];
        s0 += fmaxf(acc2[nf][0] + bv, 0.f) * w3v;
        s1 += fmaxf(acc2[nf][1] + bv, 0.f) * w3v;
        s2 += fmaxf(acc2[nf][2] + bv, 0.f) * w3v;
        s3 += fmaxf(acc2[nf][3] + bv, 0.f) * w3v;
    }
    #pragma unroll
    for (int o = 1; o < 16; o <<= 1) {
        s0 += __shfl_xor(s0, o);
        s1 += __shfl_xor(s1, o);
        s2 += __shfl_xor(s2, o);
        s3 += __shfl_xor(s3, o);
    }
    if (lr == 0) {
        const int rb = p0 + w * 16 + lq * 4;
        const float bb = b3[0];
        if (rb + 0 < P_N) out[rb + 0] = s0 + bb;
        if (rb + 1 < P_N) out[rb + 1] = s1 + bb;
        if (rb + 2 < P_N) out[rb + 2] = s2 + bb;
        if (rb + 3 < P_N) out[rb + 3] = s3 + bb;
    }
}

extern "C" void kernel_launch(void* const* d_in, const int* in_sizes, int n_in,
                              void* d_out, int out_size, void* d_ws, size_t ws_size,
                              hipStream_t stream)
{
    const float* feats[4] = {(const float*)d_in[0], (const float*)d_in[4], (const float*)d_in[8],  (const float*)d_in[12]};
    const int*   idxs[4]  = {(const int*)d_in[1],   (const int*)d_in[5],   (const int*)d_in[9],   (const int*)d_in[13]};
    const float* Ws[4]    = {(const float*)d_in[2], (const float*)d_in[6], (const float*)d_in[10], (const float*)d_in[14]};
    const float* bs[4]    = {(const float*)d_in[3], (const float*)d_in[7], (const float*)d_in[11], (const float*)d_in[15]};
    const float* gamma = (const float*)d_in[16];
    const float* beta  = (const float*)d_in[17];
    const float* W1 = (const float*)d_in[18]; const float* b1 = (const float*)d_in[19];
    const float* W2 = (const float*)d_in[20]; const float* b2 = (const float*)d_in[21];
    const float* W3 = (const float*)d_in[22]; const float* b3 = (const float*)d_in[23];
    int Ns[4] = {in_sizes[1], in_sizes[5], in_sizes[9], in_sizes[13]};
    const int Ds[4] = {96, 160, 64, 64};

    // ws layout (bytes)
    char* ws = (char*)d_ws;
    int* counts = (int*)(ws + 0);            // 4*P ints (kept: feeds invc)
    int* offs   = (int*)(ws + 320000);
    int* curs   = (int*)(ws + 640000);       // dead after k_fill -> reused for WT1/WT2
    int* lists[4];
    lists[0] = (int*)(ws + 960000);
    lists[1] = (int*)(ws + 1360000);
    lists[2] = (int*)(ws + 2960000);
    lists[3] = (int*)(ws + 3200000);
    int* splans[4];
    splans[0] = (int*)(ws + 3520000);
    splans[1] = (int*)(ws + 3920000);
    splans[2] = (int*)(ws + 5520000);
    splans[3] = (int*)(ws + 5760000);
    ushort* WTs[4];
    WTs[0] = (ushort*)(ws + 6080000);
    WTs[1] = (ushort*)(ws + 6104576);
    WTs[2] = (ushort*)(ws + 6145536);
    WTs[3] = (ushort*)(ws + 6161920);
    float* invc   = (float*)(ws + 6178304);
    float* x      = (float*)(ws + 6498304);  // P*512 f32
    float* bnsum  = (float*)(ws + 47458304);
    float* scale  = (float*)(ws + 47462400);
    float* shiftv = (float*)(ws + 47464448);
    ushort* WT1   = (ushort*)(ws + 640000);   // overlay on curs (after fill)
    ushort* WT2   = (ushort*)(ws + 771072);   // 640000+131072

    hipMemsetAsync(counts, 0, 4 * P_N * sizeof(int), stream);
    hipMemsetAsync(bnsum, 0, 1024 * sizeof(float), stream);
    hipMemsetAsync(x, 0, (size_t)P_N * 512 * sizeof(float), stream);

    for (int tp = 0; tp < 4; ++tp) {
        int gb = (Ns[tp] + 255) / 256; if (gb > 2048) gb = 2048;
        k_count<<<gb, 256, 0, stream>>>(idxs[tp], Ns[tp], counts + tp * P_N);
    }
    k_scan<<<4, 256, 0, stream>>>(counts, offs, curs);
    for (int tp = 0; tp < 4; ++tp) {
        int gb = (Ns[tp] + 255) / 256; if (gb > 2048) gb = 2048;
        k_fill<<<gb, 256, 0, stream>>>(idxs[tp], Ns[tp], curs + tp * P_N, lists[tp], splans[tp]);
        k_prepw<<<(HD * Ds[tp] + 255) / 256, 256, 0, stream>>>(Ws[tp], WTs[tp], Ds[tp]);
    }
    // head weight prep (curs is dead now)
    k_prepw<<<(HD * 512 + 255) / 256, 256, 0, stream>>>(W1, WT1, 512);
    k_prepw<<<(HD * 128 + 255) / 256, 256, 0, stream>>>(W2, WT2, 128);

    k_enc< 96><<<(Ns[0] + 63) / 64, 256, 0, stream>>>(feats[0], WTs[0], bs[0], lists[0], splans[0], Ns[0], x, 0);
    k_enc<160><<<(Ns[1] + 63) / 64, 256, 0, stream>>>(feats[1], WTs[1], bs[1], lists[1], splans[1], Ns[1], x, 128);
    k_enc< 64><<<(Ns[2] + 63) / 64, 256, 0, stream>>>(feats[2], WTs[2], bs[2], lists[2], splans[2], Ns[2], x, 256);
    k_enc< 64><<<(Ns[3] + 63) / 64, 256, 0, stream>>>(feats[3], WTs[3], bs[3], lists[3], splans[3], Ns[3], x, 384);

    k_invc<<<(4 * P_N + 255) / 256, 256, 0, stream>>>(counts, invc);
    k_bnstats<<<256, 512, 0, stream>>>(x, invc, bnsum);
    k_bnfinal<<<1, 512, 0, stream>>>(bnsum, gamma, beta, scale, shiftv);
    k_head<<<(P_N + 63) / 64, 256, 0, stream>>>(x, invc, scale, shiftv,
                                                WT1, b1, WT2, b2, W3, b3, (float*)d_out);
}